// Round 3
// baseline (74.700 us; speedup 1.0000x reference)
//
#include <hip/hip_runtime.h>
#include <hip/hip_bf16.h>

// ChamferDistanceMatrixL2: B=32, G=64, N=32, C=3.
// out[b][g1][g2] = mean_n min_m d + mean_m min_n d, d = s1 + s2 - 2*dot.
//
// R3: packed-fp32 VALU. Same thread mapping as R2 (2 threads per output,
// m-split 16/thread, partners lane^32, 4 waves/SIMD), but the inner loop
// processes m-PAIRS as <2 x float>, so the compiler can select
// v_pk_fma_f32 / v_pk_add_f32 (2 fp32 lane-ops per instruction, gfx90a+):
//   per 2 distances: 1 pk_add + 3 pk_fma + 2 v_min (colmin) + 1 v_min3 (row)
//   ~= 3.25 VALU inst/element vs ~6 in R2  ->  kernel VALU ~10.5us -> ~6.3us.
// Math is still exact fp32 (packing changes scheduling, not values).

typedef float v2f __attribute__((ext_vector_type(2)));

__global__ __launch_bounds__(256, 4)
void chamfer_dist_kernel(const float* __restrict__ xyz1,
                         const float* __restrict__ xyz2,
                         float* __restrict__ out) {
    const int tid  = threadIdx.x;
    const int w    = tid >> 6;                       // wave in block: 0..3
    const int lane = tid & 63;
    const int mh   = lane >> 5;                      // m-half: 0..1
    const int b    = blockIdx.x >> 5;                // 0..31
    const int g1   = ((blockIdx.x & 31) << 1) | (w >> 1);   // 0..63
    const int g2   = ((w & 1) << 5) | (lane & 31);          // 0..63

    // ---- register-cache my 16 m-points of group g2 via 12 dwordx4 ----
    const float4* __restrict__ p2v =
        (const float4*)(xyz2 + (size_t)(b * 64 + g2) * 96 + mh * 48);
    float buf[48];
#pragma unroll
    for (int i = 0; i < 12; ++i) {
        const float4 v = p2v[i];
        buf[4 * i + 0] = v.x;
        buf[4 * i + 1] = v.y;
        buf[4 * i + 2] = v.z;
        buf[4 * i + 3] = v.w;
    }
    // pack m-pairs into <2 x float> lanes for v_pk_* selection
    v2f x2[8], y2[8], z2[8], s2[8];
#pragma unroll
    for (int j = 0; j < 8; ++j) {
        x2[j] = (v2f){buf[6 * j + 0], buf[6 * j + 3]};
        y2[j] = (v2f){buf[6 * j + 1], buf[6 * j + 4]};
        z2[j] = (v2f){buf[6 * j + 2], buf[6 * j + 5]};
        s2[j] = __builtin_elementwise_fma(
                    x2[j], x2[j],
                    __builtin_elementwise_fma(y2[j], y2[j], z2[j] * z2[j]));
    }

    v2f colmin[8];
#pragma unroll
    for (int j = 0; j < 8; ++j) colmin[j] = (v2f){3.0e38f, 3.0e38f};

    const float* __restrict__ p1 = xyz1 + (size_t)(b * 64 + g1) * 96;
    float sum1 = 0.0f;

#pragma unroll 4
    for (int n = 0; n < 32; ++n) {
        const float x1 = p1[3 * n + 0];   // wave-uniform address -> 1 line
        const float y1 = p1[3 * n + 1];
        const float z1 = p1[3 * n + 2];
        const float s1 = fmaf(x1, x1, fmaf(y1, y1, z1 * z1));
        const v2f av = (v2f){-2.0f * x1, -2.0f * x1};
        const v2f cv = (v2f){-2.0f * y1, -2.0f * y1};
        const v2f ev = (v2f){-2.0f * z1, -2.0f * z1};
        const v2f s1v = (v2f){s1, s1};

        float rmin = 3.0e38f;
#pragma unroll
        for (int j = 0; j < 8; ++j) {
            const v2f base = s1v + s2[j];                        // v_pk_add_f32
            const v2f t = __builtin_elementwise_fma(
                              av, x2[j],
                              __builtin_elementwise_fma(
                                  cv, y2[j],
                                  __builtin_elementwise_fma(ev, z2[j], base)));
            colmin[j] = __builtin_elementwise_min(colmin[j], t);
            rmin = fminf(rmin, fminf(t.x, t.y));                 // v_min3_f32
        }
        // merge with partner's half (lane^32, same wave) -> full row min
        sum1 += fminf(rmin, __shfl_xor(rmin, 32, 64));
    }

    // colmin complete (my 16 m's, all n): pairwise sums
    v2f cs = colmin[0];
#pragma unroll
    for (int j = 1; j < 8; ++j) cs += colmin[j];
    const float mysum2 = cs.x + cs.y;
    const float sum2 = mysum2 + __shfl_xor(mysum2, 32, 64);

    const float res = (sum1 + sum2) * (1.0f / 32.0f);
    if (mh == 0) {
        out[(size_t)(b * 64 + g1) * 64 + g2] = res;  // lanes 0..31 -> 128B coalesced
    }
}

extern "C" void kernel_launch(void* const* d_in, const int* in_sizes, int n_in,
                              void* d_out, int out_size, void* d_ws, size_t ws_size,
                              hipStream_t stream) {
    const float* xyz1 = (const float*)d_in[0];
    const float* xyz2 = (const float*)d_in[1];
    float* out = (float*)d_out;

    dim3 grid(1024);  // 32 b * 32 g1-pairs
    dim3 block(256);  // 4 waves: (g1 sub-pair) x (g2 half), lanes = mhalf x 32 g2
    chamfer_dist_kernel<<<grid, block, 0, stream>>>(xyz1, xyz2, out);
}